// Round 1
// baseline (710.932 us; speedup 1.0000x reference)
//
#include <hip/hip_runtime.h>

// SelfAttention: x[8,256,64,64] fp32, W[256,256] fp32.
// sim = (x_tok . x_tok)/16 -> softmax -> ctx = attn @ x -> out = W @ ctx.
// Strategy: bf16 MFMA flash attention. ws layout:
//   xT   [b][N][C] bf16 @ 0        (16 MB)  tokens-major (Q, K)
//   xC   [b][C][N] bf16 @ 16 MB    (16 MB)  channel-major (V)
//   ctxT [b][N][C] bf16 @ 32 MB    (16 MB)
//   Wb   [o][c]    bf16 @ 48 MB    (128 KB)
// total ~50.5 MB of d_ws.

typedef __attribute__((ext_vector_type(8))) short short8;
typedef __attribute__((ext_vector_type(4))) float floatx4;

#define N_TOK 4096
#define C_DIM 256

__device__ __forceinline__ unsigned short f2bf(float f) {
  unsigned int u = __builtin_bit_cast(unsigned int, f);
  u += 0x7fffu + ((u >> 16) & 1u);
  return (unsigned short)(u >> 16);
}

__device__ __forceinline__ floatx4 mfma16(short8 a, short8 b, floatx4 c) {
  return __builtin_amdgcn_mfma_f32_16x16x32_bf16(a, b, c, 0, 0, 0);
}

// ---- K1a: x[b][c][i] fp32 -> xT[b][i][c] bf16 and xC[b][c][i] bf16 ----
__global__ __launch_bounds__(256) void transpose_conv(
    const float* __restrict__ x, unsigned short* __restrict__ xT,
    unsigned short* __restrict__ xC) {
  __shared__ float tile[32][33];
  const int b = blockIdx.z;
  const int i0 = blockIdx.x * 32, c0 = blockIdx.y * 32;
  const int tx = threadIdx.x & 31, ty = threadIdx.x >> 5;  // ty 0..7
  const float* xb = x + (size_t)b * C_DIM * N_TOK;
#pragma unroll
  for (int p = 0; p < 4; ++p) {
    int c = c0 + ty + p * 8;
    float v = xb[(size_t)c * N_TOK + i0 + tx];
    tile[ty + p * 8][tx] = v;
    xC[((size_t)b * C_DIM + c) * N_TOK + i0 + tx] = f2bf(v);
  }
  __syncthreads();
#pragma unroll
  for (int p = 0; p < 4; ++p) {
    int i = i0 + ty + p * 8;
    xT[((size_t)b * N_TOK + i) * C_DIM + c0 + tx] = f2bf(tile[tx][ty + p * 8]);
  }
}

// ---- K1b: W fp32 -> bf16 ----
__global__ __launch_bounds__(256) void wconv(const float* __restrict__ W,
                                             unsigned short* __restrict__ Wb) {
  int idx = blockIdx.x * 256 + threadIdx.x;
  Wb[idx] = f2bf(W[idx]);
}

// ---- K2: flash attention. grid 512 (=64 qtiles x 8 batches), 256 thr ----
__global__ __launch_bounds__(256) void attn_kernel(
    const unsigned short* __restrict__ xT, const unsigned short* __restrict__ xC,
    unsigned short* __restrict__ ctxT) {
  const int bid = blockIdx.x;
  const int b = bid & 7;      // batch == XCD -> per-batch L2 locality
  const int qt = bid >> 3;
  const int lane = threadIdx.x & 63;
  const int w = threadIdx.x >> 6;
  const int qbase = qt * 64 + w * 16;
  const int l15 = lane & 15, lhi = lane >> 4;
  const unsigned short* xTb = xT + (size_t)b * N_TOK * C_DIM;
  const unsigned short* xCb = xC + (size_t)b * N_TOK * C_DIM;

  __shared__ unsigned short tileK_s[64 * C_DIM];   // [j][c] swizzled, 32 KB
  __shared__ unsigned short tileV_s[C_DIM * 64];   // [c][j] swizzled, 32 KB
  __shared__ unsigned short Plds[4][16 * 64];      // per-wave P, 8 KB
  char* tK = (char*)tileK_s;
  char* tV = (char*)tileV_s;
  char* myP = (char*)(&Plds[w][0]);

  // Q fragments: A[m=l15][k = ks*32 + lhi*8 + t]
  short8 q[8];
  {
    const unsigned short* base = xTb + (size_t)(qbase + l15) * C_DIM + lhi * 8;
#pragma unroll
    for (int ks = 0; ks < 8; ++ks) q[ks] = *(const short8*)(base + ks * 32);
  }

  floatx4 acc[16];
#pragma unroll
  for (int i = 0; i < 16; ++i) acc[i] = (floatx4){0.f, 0.f, 0.f, 0.f};
  float mrow[4] = {-1e30f, -1e30f, -1e30f, -1e30f};
  float lrow[4] = {0.f, 0.f, 0.f, 0.f};
  const float SC = 0.09016844005556021f;  // log2(e) / sqrt(256)

  for (int jt = 0; jt < N_TOK; jt += 64) {
    __syncthreads();  // previous tile fully consumed
    // stage K tile [64j][256c] and V tile [256c][64j], both XOR-swizzled
#pragma unroll
    for (int k = 0; k < 8; ++k) {
      int ch = threadIdx.x + k * 256;
      int j = ch >> 5, c8 = ch & 31;
      short8 vk = *(const short8*)(xTb + (size_t)(jt + j) * C_DIM + c8 * 8);
      *(short8*)(tK + ((j * 512 + c8 * 16) ^ ((j & 7) << 4))) = vk;
      int c = ch >> 3, j8 = ch & 7;
      short8 vv = *(const short8*)(xCb + (size_t)c * N_TOK + jt + j8 * 8);
      *(short8*)(tV + ((c * 128 + j8 * 16) ^ ((c & 7) << 4))) = vv;
    }
    __syncthreads();

    // S = Q K^T  (16 q rows x 64 j per wave)
    floatx4 s[4];
#pragma unroll
    for (int jb = 0; jb < 4; ++jb) s[jb] = (floatx4){0.f, 0.f, 0.f, 0.f};
#pragma unroll
    for (int ks = 0; ks < 8; ++ks) {
#pragma unroll
      for (int jb = 0; jb < 4; ++jb) {
        int j = jb * 16 + l15;
        short8 kf = *(const short8*)(tK + ((j * 512 + ks * 64 + lhi * 16) ^ ((j & 7) << 4)));
        s[jb] = mfma16(q[ks], kf, s[jb]);
      }
    }

    // online softmax; lane holds cols j=jb*16+l15, rows lhi*4+r
    float alpha[4];
#pragma unroll
    for (int r = 0; r < 4; ++r) {
      float a0 = fmaxf(s[0][r], s[1][r]);
      float a1 = fmaxf(s[2][r], s[3][r]);
      float rm = fmaxf(a0, a1) * SC;
      rm = fmaxf(rm, __shfl_xor(rm, 1));
      rm = fmaxf(rm, __shfl_xor(rm, 2));
      rm = fmaxf(rm, __shfl_xor(rm, 4));
      rm = fmaxf(rm, __shfl_xor(rm, 8));
      float mn = fmaxf(mrow[r], rm);
      alpha[r] = exp2f(mrow[r] - mn);
      mrow[r] = mn;
      float rs = 0.f;
#pragma unroll
      for (int jb = 0; jb < 4; ++jb) {
        float p = exp2f(s[jb][r] * SC - mn);
        s[jb][r] = p;
        rs += p;
      }
      rs += __shfl_xor(rs, 1);
      rs += __shfl_xor(rs, 2);
      rs += __shfl_xor(rs, 4);
      rs += __shfl_xor(rs, 8);
      lrow[r] = lrow[r] * alpha[r] + rs;
    }

    // P (C/D layout) -> per-wave LDS (intra-wave, in-order: no barrier)
#pragma unroll
    for (int r = 0; r < 4; ++r) {
      int row = lhi * 4 + r;
#pragma unroll
      for (int jb = 0; jb < 4; ++jb)
        *(unsigned short*)(myP + row * 128 + (jb * 16 + l15) * 2) = f2bf(s[jb][r]);
    }

    // rescale O
#pragma unroll
    for (int cb = 0; cb < 16; ++cb) {
#pragma unroll
      for (int r = 0; r < 4; ++r) acc[cb][r] *= alpha[r];
    }

    // P as A fragments: A[m=l15][k=j]
    short8 pa0 = *(const short8*)(myP + l15 * 128 + lhi * 16);
    short8 pa1 = *(const short8*)(myP + l15 * 128 + 64 + lhi * 16);

    // O += P V : B[k=j][n=c] from V tile ([c][j] layout -> j contiguous)
#pragma unroll
    for (int cb = 0; cb < 16; ++cb) {
      int c = cb * 16 + l15;
      short8 v0 = *(const short8*)(tV + ((c * 128 + lhi * 16) ^ ((c & 7) << 4)));
      short8 v1 = *(const short8*)(tV + ((c * 128 + 64 + lhi * 16) ^ ((c & 7) << 4)));
      acc[cb] = mfma16(pa0, v0, acc[cb]);
      acc[cb] = mfma16(pa1, v1, acc[cb]);
    }
  }

  // epilogue: O /= l, store bf16 ctxT[b][i][c]
#pragma unroll
  for (int r = 0; r < 4; ++r) {
    float inv = 1.0f / lrow[r];
    int i = qbase + lhi * 4 + r;
    unsigned short* orow = ctxT + ((size_t)b * N_TOK + i) * C_DIM;
#pragma unroll
    for (int cb = 0; cb < 16; ++cb) orow[cb * 16 + l15] = f2bf(acc[cb][r] * inv);
  }
}

// ---- K3: out[b][o][i] = sum_c W[o][c] * ctx[c][i]  via outT = ctxT x W^T ----
__global__ __launch_bounds__(256) void outgemm(
    const unsigned short* __restrict__ ctxT, const unsigned short* __restrict__ Wb,
    float* __restrict__ out) {
  const int bid = blockIdx.x;
  const int b = bid & 7;
  const int it = bid >> 3;
  const int lane = threadIdx.x & 63;
  const int w = threadIdx.x >> 6;
  const int ibase = it * 64 + w * 16;
  const int l15 = lane & 15, lhi = lane >> 4;
  const unsigned short* cbase = ctxT + (size_t)b * N_TOK * C_DIM;

  floatx4 acc[16];
#pragma unroll
  for (int i = 0; i < 16; ++i) acc[i] = (floatx4){0.f, 0.f, 0.f, 0.f};

#pragma unroll
  for (int ks = 0; ks < 8; ++ks) {
    short8 a = *(const short8*)(cbase + (size_t)(ibase + l15) * C_DIM + ks * 32 + lhi * 8);
#pragma unroll
    for (int ob = 0; ob < 16; ++ob) {
      short8 bw = *(const short8*)(Wb + (size_t)(ob * 16 + l15) * C_DIM + ks * 32 + lhi * 8);
      acc[ob] = mfma16(a, bw, acc[ob]);
    }
  }
  float* outb = out + (size_t)b * C_DIM * N_TOK;
#pragma unroll
  for (int ob = 0; ob < 16; ++ob) {
#pragma unroll
    for (int r = 0; r < 4; ++r) {
      int o = ob * 16 + l15;
      int i = ibase + lhi * 4 + r;
      outb[(size_t)o * N_TOK + i] = acc[ob][r];
    }
  }
}

extern "C" void kernel_launch(void* const* d_in, const int* in_sizes, int n_in,
                              void* d_out, int out_size, void* d_ws, size_t ws_size,
                              hipStream_t stream) {
  const float* x = (const float*)d_in[0];
  const float* W = (const float*)d_in[1];
  float* out = (float*)d_out;
  char* ws = (char*)d_ws;
  const size_t SZ = (size_t)8 * N_TOK * C_DIM * 2;  // 16 MB per bf16 tensor
  unsigned short* xT = (unsigned short*)(ws);
  unsigned short* xC = (unsigned short*)(ws + SZ);
  unsigned short* ctxT = (unsigned short*)(ws + 2 * SZ);
  unsigned short* Wb = (unsigned short*)(ws + 3 * SZ);

  hipLaunchKernelGGL(transpose_conv, dim3(N_TOK / 32, C_DIM / 32, 8), dim3(256), 0,
                     stream, x, xT, xC);
  hipLaunchKernelGGL(wconv, dim3((C_DIM * C_DIM) / 256), dim3(256), 0, stream, W, Wb);
  hipLaunchKernelGGL(attn_kernel, dim3(512), dim3(256), 0, stream, xT, xC, ctxT);
  hipLaunchKernelGGL(outgemm, dim3(512), dim3(256), 0, stream, ctxT, Wb, out);
}

// Round 2
// 258.354 us; speedup vs baseline: 2.7518x; 2.7518x over previous
//
#include <hip/hip_runtime.h>

// SelfAttention: x[8,256,64,64] fp32, W[256,256] fp32.
// R2: 32x32x16 MFMA flash attention, 32 q-rows/wave, S^T (swapped QK^T),
// in-register P via cvt_pk_bf16 + permlane32_swap, double-buffered JT=32
// K/V LDS tiles (1 barrier/tile), defer-max, 1/l folded into out-GEMM.
// ws: xT[b][N][C] bf16 (16MB) | xC[b][C][N] bf16 (16MB) | ctxT[b][N][C] bf16
// unnormalized (16MB) | Wb bf16 (128KB) | Ld f32 [b][N] (128KB)

typedef __attribute__((ext_vector_type(8))) short short8;
typedef __attribute__((ext_vector_type(4))) float floatx4;
typedef __attribute__((ext_vector_type(16))) float floatx16;
typedef __attribute__((ext_vector_type(4))) int intx4;

#define N_TOK 4096
#define C_DIM 256
#define JT 32
#define NT (N_TOK / JT)

__device__ __forceinline__ unsigned short f2bf(float f) {
  unsigned int u = __builtin_bit_cast(unsigned int, f);
  u += 0x7fffu + ((u >> 16) & 1u);
  return (unsigned short)(u >> 16);
}

__device__ __forceinline__ floatx16 mfma32(short8 a, short8 b, floatx16 c) {
  return __builtin_amdgcn_mfma_f32_32x32x16_bf16(a, b, c, 0, 0, 0);
}
__device__ __forceinline__ floatx4 mfma16(short8 a, short8 b, floatx4 c) {
  return __builtin_amdgcn_mfma_f32_16x16x32_bf16(a, b, c, 0, 0, 0);
}
__device__ __forceinline__ unsigned cvtpk(float lo, float hi) {
  unsigned d;
  asm("v_cvt_pk_bf16_f32 %0, %1, %2" : "=v"(d) : "v"(lo), "v"(hi));
  return d;
}
__device__ __forceinline__ void swap32(unsigned& a, unsigned& b) {
  asm("v_permlane32_swap_b32 %0, %1" : "+v"(a), "+v"(b));
}

// ---- K1a: x[b][c][i] fp32 -> xT[b][i][c] bf16 and xC[b][c][i] bf16 ----
__global__ __launch_bounds__(256) void transpose_conv(
    const float* __restrict__ x, unsigned short* __restrict__ xT,
    unsigned short* __restrict__ xC) {
  __shared__ float tile[32][33];
  const int b = blockIdx.z;
  const int i0 = blockIdx.x * 32, c0 = blockIdx.y * 32;
  const int tx = threadIdx.x & 31, ty = threadIdx.x >> 5;  // ty 0..7
  const float* xb = x + (size_t)b * C_DIM * N_TOK;
#pragma unroll
  for (int p = 0; p < 4; ++p) {
    int c = c0 + ty + p * 8;
    float v = xb[(size_t)c * N_TOK + i0 + tx];
    tile[ty + p * 8][tx] = v;
    xC[((size_t)b * C_DIM + c) * N_TOK + i0 + tx] = f2bf(v);
  }
  __syncthreads();
#pragma unroll
  for (int p = 0; p < 4; ++p) {
    int i = i0 + ty + p * 8;
    xT[((size_t)b * N_TOK + i) * C_DIM + c0 + tx] = f2bf(tile[tx][ty + p * 8]);
  }
}

// ---- K1b: W fp32 -> bf16 ----
__global__ __launch_bounds__(256) void wconv(const float* __restrict__ W,
                                             unsigned short* __restrict__ Wb) {
  int idx = blockIdx.x * 256 + threadIdx.x;
  Wb[idx] = f2bf(W[idx]);
}

// ---- K2: flash attention. grid 256 (=32 qtiles x 8 batches), 256 thr ----
// Per wave: 32 q-rows. Per block: 128 q-rows. S^T = mfma(K, Q).
__global__ __launch_bounds__(256, 1) void attn_kernel(
    const unsigned short* __restrict__ xT, const unsigned short* __restrict__ xC,
    unsigned short* __restrict__ ctxT, float* __restrict__ Ld) {
  const int bid = blockIdx.x;
  const int b = bid & 7;  // batch == XCD -> per-batch L2 locality
  const int qt = bid >> 3;
  const int tid = threadIdx.x;
  const int lane = tid & 63;
  const int w = tid >> 6;
  const int l31 = lane & 31;
  const int h = lane >> 5;
  const unsigned short* xTb = xT + (size_t)b * N_TOK * C_DIM;
  const unsigned short* xCb = xC + (size_t)b * N_TOK * C_DIM;
  const int qrow = qt * 128 + w * 32 + l31;

  __shared__ char lds[2][32768];  // per buf: K tile 16KB [32j][256c], V 16KB [256c][32j]

  // Q B-fragments: B[k][n]: n=i=l31, k = ks*16 + h*8 + t
  short8 q[16];
  {
    const unsigned short* qp = xTb + (size_t)qrow * C_DIM + h * 8;
#pragma unroll
    for (int ks = 0; ks < 16; ++ks) q[ks] = *(const short8*)(qp + ks * 16);
  }

  floatx16 acc[8];
#pragma unroll
  for (int ct = 0; ct < 8; ++ct)
#pragma unroll
    for (int r = 0; r < 16; ++r) acc[ct][r] = 0.f;
  float m = -1e30f, lsum = 0.f;
  const float SC = 0.09016844005556021f;  // log2(e)/16

  // staging thread->element maps (id = it*256 + tid)
  const int kc16 = tid & 31;     // K chunk col (c16), id&31
  const int kjb = tid >> 5;      // K j = it*8 + kjb
  const int vjc = tid & 3;       // V j-chunk
  const int vcb = tid >> 2;      // V c = it*64 + vcb

  short8 gK[4], gV[4];
  // prologue: load + write tile 0
#pragma unroll
  for (int it = 0; it < 4; ++it) {
    gK[it] = *(const short8*)(xTb + (size_t)(it * 8 + kjb) * C_DIM + kc16 * 8);
    gV[it] = *(const short8*)(xCb + (size_t)(it * 64 + vcb) * N_TOK + vjc * 8);
  }
#pragma unroll
  for (int it = 0; it < 4; ++it) {
    int j = it * 8 + kjb;
    *(short8*)(lds[0] + ((j * 512 + kc16 * 16) ^ ((j & 31) << 4))) = gK[it];
    int c = it * 64 + vcb;
    *(short8*)(lds[0] + 16384 + ((c * 64 + vjc * 16) ^ ((c & 3) << 4))) = gV[it];
  }
  __syncthreads();

  for (int t = 0; t < NT; ++t) {
    const char* Kb = lds[t & 1];
    const char* Vb = lds[t & 1] + 16384;
    // T14: issue next tile's global loads before compute
    if (t + 1 < NT) {
      const int jn = (t + 1) * JT;
#pragma unroll
      for (int it = 0; it < 4; ++it) {
        gK[it] = *(const short8*)(xTb + (size_t)(jn + it * 8 + kjb) * C_DIM + kc16 * 8);
        gV[it] = *(const short8*)(xCb + (size_t)(it * 64 + vcb) * N_TOK + jn + vjc * 8);
      }
    }
    // S^T[j][i] = sum_c K[j][c] Q[i][c] : A = K (m=j), B = Q (n=i)
    floatx16 s;
#pragma unroll
    for (int r = 0; r < 16; ++r) s[r] = 0.f;
#pragma unroll
    for (int ks = 0; ks < 16; ++ks) {
      short8 kf = *(const short8*)(Kb + ((l31 * 512 + ks * 32 + h * 16) ^ (l31 << 4)));
      s = mfma32(kf, q[ks], s);
    }
    // online softmax: lane owns q-row i=l31; j = (r&3)+8*(r>>2)+4*h (16 of 32)
    float mx = s[0];
#pragma unroll
    for (int r = 1; r < 16; ++r) mx = fmaxf(mx, s[r]);
    mx = fmaxf(mx, __shfl_xor(mx, 32));
    float pm = mx * SC;
    bool need = __any(pm > m + 8.0f) != 0;  // defer-max (T13)
    float mn = need ? fmaxf(m, pm) : m;
    float al = need ? exp2f(m - mn) : 1.0f;
    m = mn;
    float p[16];
    float rs = 0.f;
#pragma unroll
    for (int r = 0; r < 16; ++r) {
      p[r] = exp2f(s[r] * SC - mn);
      rs += p[r];
    }
    rs += __shfl_xor(rs, 32);
    lsum = lsum * al + rs;
    if (need) {  // wave-uniform; rare after warmup
#pragma unroll
      for (int r = 0; r < 16; ++r) {
        float ar = __shfl(al, (r & 3) + 8 * (r >> 2) + 4 * h);
#pragma unroll
        for (int ct = 0; ct < 8; ++ct) acc[ct][r] *= ar;
      }
    }
    // P^T (D-layout) -> PV A-fragments in-register: cvt_pk + permlane32_swap
    unsigned pk[8];
#pragma unroll
    for (int pi = 0; pi < 8; ++pi) pk[pi] = cvtpk(p[2 * pi], p[2 * pi + 1]);
    swap32(pk[0], pk[2]);
    swap32(pk[1], pk[3]);
    swap32(pk[4], pk[6]);
    swap32(pk[5], pk[7]);
    intx4 w0v = {(int)pk[0], (int)pk[1], (int)pk[2], (int)pk[3]};
    intx4 w1v = {(int)pk[4], (int)pk[5], (int)pk[6], (int)pk[7]};
    short8 pa0 = __builtin_bit_cast(short8, w0v);  // k = j 0..15
    short8 pa1 = __builtin_bit_cast(short8, w1v);  // k = j 16..31
    // O[i][c] += P[i][j] V[j][c] : B from V tile [c][j]
#pragma unroll
    for (int ct = 0; ct < 8; ++ct) {
      int c = ct * 32 + l31;
      int swz = (l31 & 3) << 4;
      short8 v0 = *(const short8*)(Vb + ((c * 64 + h * 16) ^ swz));
      short8 v1 = *(const short8*)(Vb + ((c * 64 + 32 + h * 16) ^ swz));
      acc[ct] = mfma32(pa0, v0, acc[ct]);
      acc[ct] = mfma32(pa1, v1, acc[ct]);
    }
    // write staged tile t+1 into other buffer; one barrier per tile
    if (t + 1 < NT) {
      char* nb = lds[(t + 1) & 1];
#pragma unroll
      for (int it = 0; it < 4; ++it) {
        int j = it * 8 + kjb;
        *(short8*)(nb + ((j * 512 + kc16 * 16) ^ ((j & 31) << 4))) = gK[it];
        int c = it * 64 + vcb;
        *(short8*)(nb + 16384 + ((c * 64 + vjc * 16) ^ ((c & 3) << 4))) = gV[it];
      }
    }
    __syncthreads();
  }

  // epilogue: store unnormalized O (bf16) + row sums l (f32)
  if (lane < 32) Ld[(size_t)b * N_TOK + qt * 128 + w * 32 + l31] = lsum;
  unsigned short* cb = ctxT + ((size_t)b * N_TOK + qt * 128 + w * 32) * C_DIM;
#pragma unroll
  for (int r = 0; r < 16; ++r) {
    int ri = (r & 3) + 8 * (r >> 2) + 4 * h;
#pragma unroll
    for (int ct = 0; ct < 8; ++ct)
      cb[(size_t)ri * C_DIM + ct * 32 + l31] = f2bf(acc[ct][r]);
  }
}

// ---- K3: out[b][o][i] = (1/l[i]) * sum_c W[o][c] * ctxT[i][c] ----
__global__ __launch_bounds__(256) void outgemm(
    const unsigned short* __restrict__ ctxT, const unsigned short* __restrict__ Wb,
    const float* __restrict__ Ld, float* __restrict__ out) {
  const int bid = blockIdx.x;
  const int b = bid & 7;
  const int it = bid >> 3;
  const int lane = threadIdx.x & 63;
  const int w = threadIdx.x >> 6;
  const int ibase = it * 64 + w * 16;
  const int l15 = lane & 15, lhi = lane >> 4;
  const unsigned short* cbase = ctxT + (size_t)b * N_TOK * C_DIM;

  float li[4];
#pragma unroll
  for (int r = 0; r < 4; ++r)
    li[r] = 1.0f / Ld[(size_t)b * N_TOK + ibase + lhi * 4 + r];

  floatx4 acc[16];
#pragma unroll
  for (int i = 0; i < 16; ++i) acc[i] = (floatx4){0.f, 0.f, 0.f, 0.f};

#pragma unroll
  for (int ks = 0; ks < 8; ++ks) {
    short8 a = *(const short8*)(cbase + (size_t)(ibase + l15) * C_DIM + ks * 32 + lhi * 8);
#pragma unroll
    for (int ob = 0; ob < 16; ++ob) {
      short8 bw = *(const short8*)(Wb + (size_t)(ob * 16 + l15) * C_DIM + ks * 32 + lhi * 8);
      acc[ob] = mfma16(a, bw, acc[ob]);
    }
  }
  float* outb = out + (size_t)b * C_DIM * N_TOK;
#pragma unroll
  for (int ob = 0; ob < 16; ++ob) {
#pragma unroll
    for (int r = 0; r < 4; ++r) {
      int o = ob * 16 + l15;
      int i = ibase + lhi * 4 + r;
      outb[(size_t)o * N_TOK + i] = acc[ob][r] * li[r];
    }
  }
}

extern "C" void kernel_launch(void* const* d_in, const int* in_sizes, int n_in,
                              void* d_out, int out_size, void* d_ws, size_t ws_size,
                              hipStream_t stream) {
  const float* x = (const float*)d_in[0];
  const float* W = (const float*)d_in[1];
  float* out = (float*)d_out;
  char* ws = (char*)d_ws;
  const size_t SZ = (size_t)8 * N_TOK * C_DIM * 2;  // 16 MB per bf16 tensor
  unsigned short* xT = (unsigned short*)(ws);
  unsigned short* xC = (unsigned short*)(ws + SZ);
  unsigned short* ctxT = (unsigned short*)(ws + 2 * SZ);
  unsigned short* Wb = (unsigned short*)(ws + 3 * SZ);
  float* Ld = (float*)(ws + 3 * SZ + C_DIM * C_DIM * 2);

  hipLaunchKernelGGL(transpose_conv, dim3(N_TOK / 32, C_DIM / 32, 8), dim3(256), 0,
                     stream, x, xT, xC);
  hipLaunchKernelGGL(wconv, dim3((C_DIM * C_DIM) / 256), dim3(256), 0, stream, W, Wb);
  hipLaunchKernelGGL(attn_kernel, dim3(256), dim3(256), 0, stream, xT, xC, ctxT, Ld);
  hipLaunchKernelGGL(outgemm, dim3(512), dim3(256), 0, stream, ctxT, Wb, Ld, out);
}